// Round 1
// baseline (3316.806 us; speedup 1.0000x reference)
//
#include <hip/hip_runtime.h>
#include <cstdint>
#include <cstddef>

// CCDecoder: 16-step input-feeding LSTM + Luong attention decoder.
// B=256, S=512, T=16, H=1024, E=512.
// Plan: pre-convert ctx/weights/emb to bf16 in ws; per step:
//   [gates GEMM (MFMA bf16)] -> [LSTM pointwise] -> [W_in GEMM] ->
//   [masked softmax attention over ctx_bf16] -> [W_out GEMM + tanh -> out]
// ws layout (bytes): see kernel_launch. Needs ~308MB for bf16-ctx path,
// ~40MB minimum (falls back to fp32-ctx attention reads).

#define B_ 256
#define S_ 512
#define T_ 16
#define H_ 1024
#define E_ 512

typedef unsigned short u16;
using short8 = __attribute__((ext_vector_type(8))) short;
using f32x4  = __attribute__((ext_vector_type(4))) float;

__device__ __forceinline__ float bf2f(u16 u) {
  union { uint32_t i; float f; } v; v.i = ((uint32_t)u) << 16; return v.f;
}
__device__ __forceinline__ u16 f2bf(float f) {
  union { uint32_t i; float f; } v; v.f = f;
  uint32_t r = v.i + 0x7fffu + ((v.i >> 16) & 1u);
  return (u16)(r >> 16);
}
__device__ __forceinline__ float sigmoidf_(float x) { return 1.f / (1.f + __expf(-x)); }

__device__ __forceinline__ void gload_lds16(const void* g, void* l) {
  __builtin_amdgcn_global_load_lds(
      (const __attribute__((address_space(1))) void*)g,
      (__attribute__((address_space(3))) void*)l, 16, 0, 0);
}

// ---------------------------------------------------------------- converts
__global__ __launch_bounds__(256) void cvt_bf16(const float4* __restrict__ src,
                                                ushort4* __restrict__ dst, int n4) {
  for (int i = blockIdx.x * 256 + threadIdx.x; i < n4; i += gridDim.x * 256) {
    float4 v = src[i];
    ushort4 o; o.x = f2bf(v.x); o.y = f2bf(v.y); o.z = f2bf(v.z); o.w = f2bf(v.w);
    dst[i] = o;
  }
}

__global__ __launch_bounds__(256) void init_state(const float* __restrict__ h0,
                                                  const float* __restrict__ c0,
                                                  float* __restrict__ h32,
                                                  float* __restrict__ c,
                                                  u16* __restrict__ hbf,
                                                  u16* __restrict__ htbf) {
  int idx = blockIdx.x * 256 + threadIdx.x;
  float hv = h0[idx];
  h32[idx] = hv;
  c[idx] = c0[idx];
  u16 hb = f2bf(hv);
  hbf[idx] = hb;
  htbf[idx] = hb;
}

// ---------------------------------------------------------------- GEMM
// C[M=256, N] = sum_regions A_r (256 x klen_r, bf16) * B_r^T (N x klen_r, bf16)
// BM=256 (full M), BN=32 per block, 4 waves each owning 64 rows x 32 cols.
// LDS tiles XOR-swizzled (chunk ^= row&7) to kill the 128B-row-stride conflict.
struct Region {
  const u16* A; int lda;   // activation rows (b), region-local k
  const u16* Bw; int ldb;  // weight rows (n), region-local k (Bw pre-offset)
  int klen;                // multiple of 64
};

template <int EPI>  // 0: fp32 store (gates), 1: bf16 store (target), 2: tanh -> fp32 out + bf16 htilde
__global__ __launch_bounds__(256) void gemm_ms(Region r0, Region r1, Region r2, int nreg,
                                               float* __restrict__ C, int ldc,
                                               u16* __restrict__ C2) {
  __shared__ u16 smA[256 * 64];
  __shared__ u16 smB[32 * 64];
  const int tid = threadIdx.x;
  const int lane = tid & 63;
  const int wave = tid >> 6;
  const int n0 = blockIdx.x * 32;
  f32x4 acc[4][2] = {};
  Region rr[3] = { r0, r1, r2 };
  for (int rg = 0; rg < nreg; ++rg) {
    const u16* A = rr[rg].A;
    const int lda = rr[rg].lda;
    const u16* Bw = rr[rg].Bw;
    const int ldb = rr[rg].ldb;
    const int klen = rr[rg].klen;
    for (int kr = 0; kr < klen; kr += 64) {
      __syncthreads();  // previous tile fully consumed
      // A: 256x64 bf16 = 2048 16B-chunks, 8 per thread. Swizzle: store logical
      // k-chunk q at LDS chunk-col (q ^ (row&7)) -> fetch global q = c ^ (row&7).
#pragma unroll
      for (int j = 0; j < 8; ++j) {
        const int chunk = j * 256 + tid;
        const int row = chunk >> 3;
        const int q = (chunk & 7) ^ (row & 7);
        gload_lds16(A + (size_t)row * lda + kr + q * 8,
                    (char*)smA + (size_t)(j * 256 + wave * 64) * 16);
      }
      {  // B: 32x64 = 256 chunks, 1 per thread
        const int row = tid >> 3;
        const int q = (tid & 7) ^ (row & 7);
        gload_lds16(Bw + (size_t)(n0 + row) * ldb + kr + q * 8,
                    (char*)smB + (size_t)(wave * 64) * 16);
      }
      __syncthreads();
#pragma unroll
      for (int ks = 0; ks < 2; ++ks) {
        const int row16 = lane & 15;
        const int q = ks * 4 + (lane >> 4);  // logical 16B k-chunk for this lane
        short8 af[4], bfr[2];
#pragma unroll
        for (int mi = 0; mi < 4; ++mi) {
          const int R = wave * 64 + mi * 16 + row16;
          af[mi] = *(const short8*)((const char*)smA + (size_t)(R * 8 + (q ^ (R & 7))) * 16);
        }
#pragma unroll
        for (int ni = 0; ni < 2; ++ni) {
          const int Rn = ni * 16 + row16;
          bfr[ni] = *(const short8*)((const char*)smB + (size_t)(Rn * 8 + (q ^ (Rn & 7))) * 16);
        }
#pragma unroll
        for (int mi = 0; mi < 4; ++mi)
#pragma unroll
          for (int ni = 0; ni < 2; ++ni)
            acc[mi][ni] = __builtin_amdgcn_mfma_f32_16x16x32_bf16(af[mi], bfr[ni], acc[mi][ni], 0, 0, 0);
      }
    }
  }
  // C/D layout: col = lane&15, row = (lane>>4)*4 + r  [m89-verified]
  const int row16 = lane & 15;
  const int kg = lane >> 4;
#pragma unroll
  for (int mi = 0; mi < 4; ++mi) {
#pragma unroll
    for (int ni = 0; ni < 2; ++ni) {
#pragma unroll
      for (int r = 0; r < 4; ++r) {
        const int row = wave * 64 + mi * 16 + kg * 4 + r;
        const int col = n0 + ni * 16 + row16;
        float v = acc[mi][ni][r];
        if (EPI == 0) {
          C[(size_t)row * ldc + col] = v;
        } else if (EPI == 1) {
          C2[row * H_ + col] = f2bf(v);
        } else {
          float tv = tanhf(v);
          C[(size_t)row * ldc + col] = tv;
          C2[row * H_ + col] = f2bf(tv);
        }
      }
    }
  }
}

// ---------------------------------------------------------------- LSTM pointwise
__global__ __launch_bounds__(256) void lstm_pw(const float* __restrict__ gates,
                                               const float* __restrict__ b_ih,
                                               const float* __restrict__ b_hh,
                                               float* __restrict__ c,
                                               float* __restrict__ h32,
                                               u16* __restrict__ hbf) {
  const int idx = blockIdx.x * 256 + threadIdx.x;
  const int n = idx & (H_ - 1);
  const float* gb = gates + (size_t)(idx >> 10) * (4 * H_);
  float iv = gb[n]           + b_ih[n]           + b_hh[n];
  float fv = gb[H_ + n]      + b_ih[H_ + n]      + b_hh[H_ + n];
  float gv = gb[2 * H_ + n]  + b_ih[2 * H_ + n]  + b_hh[2 * H_ + n];
  float ov = gb[3 * H_ + n]  + b_ih[3 * H_ + n]  + b_hh[3 * H_ + n];
  iv = sigmoidf_(iv); fv = sigmoidf_(fv); gv = tanhf(gv); ov = sigmoidf_(ov);
  float cn = fv * c[idx] + iv * gv;
  c[idx] = cn;
  float hn = ov * tanhf(cn);
  h32[idx] = hn;
  hbf[idx] = f2bf(hn);
}

// ---------------------------------------------------------------- attention
// One block per batch row. Pass1: wave-per-s dot(ctx[b,s,:], target[b,:]) with
// 64-lane reduce; masked rows skipped (score stays -1e9). Then block softmax;
// pass2: thread-owns-4-columns weighted sum over s<len.
template <int ISBF>
__global__ __launch_bounds__(256) void attn_k(const void* __restrict__ ctxv,
                                              const u16* __restrict__ target,
                                              const int* __restrict__ src_len,
                                              u16* __restrict__ wbf) {
  __shared__ float sc[S_];
  __shared__ float red[8];
  const int b = blockIdx.x;
  const int tid = threadIdx.x;
  const int lane = tid & 63;
  const int wave = tid >> 6;
  const int len = src_len[b];
  sc[tid] = -1e9f;
  sc[tid + 256] = -1e9f;
  float tg[16];
  {
    const u16* tp = target + b * H_ + lane * 16;
    short8 v1 = *(const short8*)tp;
    short8 v2 = *(const short8*)(tp + 8);
#pragma unroll
    for (int j = 0; j < 8; ++j) { tg[j] = bf2f((u16)v1[j]); tg[8 + j] = bf2f((u16)v2[j]); }
  }
  __syncthreads();
  if (ISBF) {
    const u16* cb = (const u16*)ctxv + (size_t)b * (S_ * H_);
    for (int s = wave; s < len; s += 4) {
      const u16* cr = cb + (size_t)s * H_ + lane * 16;
      short8 v1 = *(const short8*)cr;
      short8 v2 = *(const short8*)(cr + 8);
      float acc = 0.f;
#pragma unroll
      for (int j = 0; j < 8; ++j) acc += bf2f((u16)v1[j]) * tg[j];
#pragma unroll
      for (int j = 0; j < 8; ++j) acc += bf2f((u16)v2[j]) * tg[8 + j];
#pragma unroll
      for (int off = 1; off < 64; off <<= 1) acc += __shfl_xor(acc, off);
      if (lane == 0) sc[s] = acc;
    }
  } else {
    const float* cb = (const float*)ctxv + (size_t)b * (S_ * H_);
    for (int s = wave; s < len; s += 4) {
      const float* cr = cb + (size_t)s * H_ + lane * 16;
      float4 v1 = *(const float4*)cr;
      float4 v2 = *(const float4*)(cr + 4);
      float4 v3 = *(const float4*)(cr + 8);
      float4 v4 = *(const float4*)(cr + 12);
      float acc = v1.x*tg[0]+v1.y*tg[1]+v1.z*tg[2]+v1.w*tg[3]
                + v2.x*tg[4]+v2.y*tg[5]+v2.z*tg[6]+v2.w*tg[7]
                + v3.x*tg[8]+v3.y*tg[9]+v3.z*tg[10]+v3.w*tg[11]
                + v4.x*tg[12]+v4.y*tg[13]+v4.z*tg[14]+v4.w*tg[15];
#pragma unroll
      for (int off = 1; off < 64; off <<= 1) acc += __shfl_xor(acc, off);
      if (lane == 0) sc[s] = acc;
    }
  }
  __syncthreads();
  float m = fmaxf(sc[tid], sc[tid + 256]);
#pragma unroll
  for (int off = 1; off < 64; off <<= 1) m = fmaxf(m, __shfl_xor(m, off));
  if (lane == 0) red[wave] = m;
  __syncthreads();
  m = fmaxf(fmaxf(red[0], red[1]), fmaxf(red[2], red[3]));
  float p0 = __expf(sc[tid] - m);        // masked entries: exp(-1e9-m) -> 0
  float p1 = __expf(sc[tid + 256] - m);
  sc[tid] = p0;
  sc[tid + 256] = p1;
  float ps = p0 + p1;
#pragma unroll
  for (int off = 1; off < 64; off <<= 1) ps += __shfl_xor(ps, off);
  if (lane == 0) red[4 + wave] = ps;
  __syncthreads();
  const float inv = 1.f / (red[4] + red[5] + red[6] + red[7]);
  float a0 = 0.f, a1 = 0.f, a2 = 0.f, a3 = 0.f;
  const int col = tid * 4;
  if (ISBF) {
    const u16* cb = (const u16*)ctxv + (size_t)b * (S_ * H_) + col;
    for (int s = 0; s < len; ++s) {
      float p = sc[s];
      ushort4 v = *(const ushort4*)(cb + (size_t)s * H_);
      a0 += p * bf2f(v.x); a1 += p * bf2f(v.y); a2 += p * bf2f(v.z); a3 += p * bf2f(v.w);
    }
  } else {
    const float* cb = (const float*)ctxv + (size_t)b * (S_ * H_) + col;
    for (int s = 0; s < len; ++s) {
      float p = sc[s];
      float4 v = *(const float4*)(cb + (size_t)s * H_);
      a0 += p * v.x; a1 += p * v.y; a2 += p * v.z; a3 += p * v.w;
    }
  }
  ushort4 o;
  o.x = f2bf(a0 * inv); o.y = f2bf(a1 * inv); o.z = f2bf(a2 * inv); o.w = f2bf(a3 * inv);
  *(ushort4*)(wbf + b * H_ + col) = o;
}

// ---------------------------------------------------------------- host
extern "C" void kernel_launch(void* const* d_in, const int* in_sizes, int n_in,
                              void* d_out, int out_size, void* d_ws, size_t ws_size,
                              hipStream_t stream) {
  const float* trg_emb = (const float*)d_in[0];
  const float* h0      = (const float*)d_in[1];
  const float* c0      = (const float*)d_in[2];
  const float* ctx     = (const float*)d_in[3];
  const int*   src_len = (const int*)d_in[4];
  const float* W_ih    = (const float*)d_in[5];
  const float* W_hh    = (const float*)d_in[6];
  const float* b_ih    = (const float*)d_in[7];
  const float* b_hh    = (const float*)d_in[8];
  const float* W_in    = (const float*)d_in[9];
  const float* W_out   = (const float*)d_in[10];
  float* out = (float*)d_out;

  char* w = (char*)d_ws;
  u16*   wWih  = (u16*)(w);                 // 4096*1536*2 = 12582912
  u16*   wWhh  = (u16*)(w + 12582912);      // 4096*1024*2 =  8388608
  u16*   wWin  = (u16*)(w + 20971520);      // 1024*1024*2 =  2097152
  u16*   wWout = (u16*)(w + 23068672);      // 1024*2048*2 =  4194304
  u16*   wemb  = (u16*)(w + 27262976);      // 256*16*512*2 = 4194304
  float* wgates= (float*)(w + 31457280);    // 256*4096*4  =  4194304
  float* wh32  = (float*)(w + 35651584);    // 256*1024*4  =  1048576
  float* wc    = (float*)(w + 36700160);    // 1048576
  u16*   whbf  = (u16*)(w + 37748736);      // 524288
  u16*   whtbf = (u16*)(w + 38273024);      // 524288
  u16*   wtgt  = (u16*)(w + 38797312);      // 524288
  u16*   wwbf  = (u16*)(w + 39321600);      // 524288
  u16*   wctx  = (u16*)(w + 39845888);      // 256*512*1024*2 = 268435456
  const bool ctx_bf = ws_size >= (size_t)39845888 + (size_t)268435456;

  auto cvt_launch = [&](const float* s, u16* d, int n) {
    int n4 = n / 4;
    int grid = (n4 + 255) / 256;
    if (grid > 4096) grid = 4096;
    cvt_bf16<<<dim3(grid), dim3(256), 0, stream>>>((const float4*)s, (ushort4*)d, n4);
  };
  cvt_launch(W_ih,  wWih,  4096 * 1536);
  cvt_launch(W_hh,  wWhh,  4096 * 1024);
  cvt_launch(W_in,  wWin,  1024 * 1024);
  cvt_launch(W_out, wWout, 1024 * 2048);
  cvt_launch(trg_emb, wemb, B_ * T_ * E_);
  if (ctx_bf) cvt_launch(ctx, wctx, B_ * S_ * H_);
  init_state<<<dim3((B_ * H_) / 256), dim3(256), 0, stream>>>(h0, c0, wh32, wc, whbf, whtbf);

  Region dummy = { nullptr, 0, nullptr, 0, 0 };
  for (int t = 0; t < T_; ++t) {
    // gates = [emb_t, htilde] @ W_ih^T + h @ W_hh^T  (biases added in lstm_pw)
    Region g0 = { wemb + (size_t)t * E_, T_ * E_, wWih,      E_ + H_, E_ };
    Region g1 = { whtbf,                 H_,      wWih + E_, E_ + H_, H_ };
    Region g2 = { whbf,                  H_,      wWhh,      H_,      H_ };
    gemm_ms<0><<<dim3((4 * H_) / 32), dim3(256), 0, stream>>>(g0, g1, g2, 3, wgates, 4 * H_, (u16*)nullptr);
    lstm_pw<<<dim3((B_ * H_) / 256), dim3(256), 0, stream>>>(wgates, b_ih, b_hh, wc, wh32, whbf);
    // target = h @ W_in^T
    Region i0 = { whbf, H_, wWin, H_, H_ };
    gemm_ms<1><<<dim3(H_ / 32), dim3(256), 0, stream>>>(i0, dummy, dummy, 1, (float*)nullptr, 0, wtgt);
    if (ctx_bf)
      attn_k<1><<<dim3(B_), dim3(256), 0, stream>>>((const void*)wctx, wtgt, src_len, wwbf);
    else
      attn_k<0><<<dim3(B_), dim3(256), 0, stream>>>((const void*)ctx, wtgt, src_len, wwbf);
    // htilde = tanh([weighted, h] @ W_out^T) -> out[:, t, :] and feed-back buffer
    Region o0 = { wwbf, H_, wWout,      2 * H_, H_ };
    Region o1 = { whbf, H_, wWout + H_, 2 * H_, H_ };
    gemm_ms<2><<<dim3(H_ / 32), dim3(256), 0, stream>>>(o0, o1, dummy, 2,
                                                        out + (size_t)t * H_, T_ * H_, whtbf);
  }
  hipMemcpyAsync(out + (size_t)B_ * T_ * H_, wh32, (size_t)B_ * H_ * sizeof(float),
                 hipMemcpyDeviceToDevice, stream);
  hipMemcpyAsync(out + (size_t)B_ * T_ * H_ + B_ * H_, wc, (size_t)B_ * H_ * sizeof(float),
                 hipMemcpyDeviceToDevice, stream);
}

// Round 2
// 2364.196 us; speedup vs baseline: 1.4029x; 1.4029x over previous
//
#include <hip/hip_runtime.h>
#include <cstdint>
#include <cstddef>

// CCDecoder: 16-step input-feeding LSTM + Luong attention decoder.
// B=256, S=512, T=16, H=1024, E=512.
// R2: online-softmax fused attention (single ctx pass, 16 waves/block);
//     GEMMs double-buffered, BM=128 (gates GEMM now fills all 256 CUs).

#define B_ 256
#define S_ 512
#define T_ 16
#define H_ 1024
#define E_ 512

typedef unsigned short u16;
using short8 = __attribute__((ext_vector_type(8))) short;
using f32x4  = __attribute__((ext_vector_type(4))) float;

__device__ __forceinline__ float bf2f(u16 u) {
  union { uint32_t i; float f; } v; v.i = ((uint32_t)u) << 16; return v.f;
}
__device__ __forceinline__ u16 f2bf(float f) {
  union { uint32_t i; float f; } v; v.f = f;
  uint32_t r = v.i + 0x7fffu + ((v.i >> 16) & 1u);
  return (u16)(r >> 16);
}
__device__ __forceinline__ float sigmoidf_(float x) { return 1.f / (1.f + __expf(-x)); }

__device__ __forceinline__ void gload_lds16(const void* g, void* l) {
  __builtin_amdgcn_global_load_lds(
      (const __attribute__((address_space(1))) void*)g,
      (__attribute__((address_space(3))) void*)l, 16, 0, 0);
}

// ---------------------------------------------------------------- converts
__global__ __launch_bounds__(256) void cvt_bf16(const float4* __restrict__ src,
                                                ushort4* __restrict__ dst, int n4) {
  for (int i = blockIdx.x * 256 + threadIdx.x; i < n4; i += gridDim.x * 256) {
    float4 v = src[i];
    ushort4 o; o.x = f2bf(v.x); o.y = f2bf(v.y); o.z = f2bf(v.z); o.w = f2bf(v.w);
    dst[i] = o;
  }
}

__global__ __launch_bounds__(256) void init_state(const float* __restrict__ h0,
                                                  const float* __restrict__ c0,
                                                  float* __restrict__ h32,
                                                  float* __restrict__ c,
                                                  u16* __restrict__ hbf,
                                                  u16* __restrict__ htbf) {
  int idx = blockIdx.x * 256 + threadIdx.x;
  float hv = h0[idx];
  h32[idx] = hv;
  c[idx] = c0[idx];
  u16 hb = f2bf(hv);
  hbf[idx] = hb;
  htbf[idx] = hb;
}

// ---------------------------------------------------------------- GEMM
// C[M=256, N] = sum_regions A_r (256 x klen_r, bf16) * B_r^T (N x klen_r, bf16)
// BM=128, BN=32. 4 waves, each 32 rows x 32 cols. Double-buffered LDS:
// stage(t+1) issued BEFORE compute(t); one __syncthreads per tile (compiler's
// barrier drain = vmcnt(0)+lgkmcnt(0)). XOR swizzle (chunk ^= row&7) kills the
// 128B-row-stride bank conflict on ds_read_b128.
struct Region {
  const u16* A; int lda;
  const u16* Bw; int ldb;
  int klen;                // multiple of 64
};

template <int EPI>  // 0: fp32 store (gates), 1: bf16 (target), 2: tanh -> fp32 out + bf16 htilde
__global__ __launch_bounds__(256) void gemm_ms(Region r0, Region r1, Region r2, int nreg,
                                               float* __restrict__ C, int ldc,
                                               u16* __restrict__ C2) {
  __shared__ u16 smA[2][128 * 64];
  __shared__ u16 smB[2][32 * 64];
  const int tid = threadIdx.x;
  const int lane = tid & 63;
  const int wave = tid >> 6;
  const int m0 = (blockIdx.x & 1) * 128;
  const int n0 = (blockIdx.x >> 1) * 32;

  Region rr[3] = { r0, r1, r2 };
  int tcnt[3];
  int nt = 0;
#pragma unroll
  for (int rg = 0; rg < 3; ++rg) { tcnt[rg] = (rg < nreg) ? (rr[rg].klen >> 6) : 0; nt += tcnt[rg]; }

  auto stage = [&](int lin, int buf) {
    int rg = 0, base = 0;
    while (lin >= base + tcnt[rg]) { base += tcnt[rg]; ++rg; }
    const int kr = (lin - base) << 6;
    const u16* A = rr[rg].A;  const int lda = rr[rg].lda;
    const u16* Bw = rr[rg].Bw; const int ldb = rr[rg].ldb;
    // A: 128x64 bf16 = 1024 16B-chunks, 4/thread. LDS chunk c holds logical
    // k-chunk (c&7)^(row&7) of row c>>3 (hardware writes lane-linear).
#pragma unroll
    for (int j = 0; j < 4; ++j) {
      const int c = j * 256 + tid;
      const int row = c >> 3;
      const int q = (c & 7) ^ (row & 7);
      gload_lds16(A + (size_t)(m0 + row) * lda + kr + q * 8,
                  (char*)&smA[buf][0] + (size_t)(j * 256 + wave * 64) * 16);
    }
    {  // B: 32x64 = 256 chunks, 1/thread
      const int row = tid >> 3;
      const int q = (tid & 7) ^ (row & 7);
      gload_lds16(Bw + (size_t)(n0 + row) * ldb + kr + q * 8,
                  (char*)&smB[buf][0] + (size_t)(wave * 64) * 16);
    }
  };

  f32x4 acc[2][2] = {};
  stage(0, 0);
  for (int ti = 0; ti < nt; ++ti) {
    const int buf = ti & 1;
    __syncthreads();                     // stage(ti) drained; prev readers done
    if (ti + 1 < nt) stage(ti + 1, buf ^ 1);
    const int row16 = lane & 15;
#pragma unroll
    for (int ks = 0; ks < 2; ++ks) {
      const int q = ks * 4 + (lane >> 4);
      short8 af[2], bfr[2];
#pragma unroll
      for (int mi = 0; mi < 2; ++mi) {
        const int R = wave * 32 + mi * 16 + row16;
        af[mi] = *(const short8*)((const char*)&smA[buf][0] + (size_t)(R * 8 + (q ^ (R & 7))) * 16);
      }
#pragma unroll
      for (int ni = 0; ni < 2; ++ni) {
        const int Rn = ni * 16 + row16;
        bfr[ni] = *(const short8*)((const char*)&smB[buf][0] + (size_t)(Rn * 8 + (q ^ (Rn & 7))) * 16);
      }
#pragma unroll
      for (int mi = 0; mi < 2; ++mi)
#pragma unroll
        for (int ni = 0; ni < 2; ++ni)
          acc[mi][ni] = __builtin_amdgcn_mfma_f32_16x16x32_bf16(af[mi], bfr[ni], acc[mi][ni], 0, 0, 0);
    }
  }
  // C/D layout: col = lane&15, row = (lane>>4)*4 + r  [m89-verified]
  const int row16 = lane & 15;
  const int kg = lane >> 4;
#pragma unroll
  for (int mi = 0; mi < 2; ++mi) {
#pragma unroll
    for (int ni = 0; ni < 2; ++ni) {
#pragma unroll
      for (int r = 0; r < 4; ++r) {
        const int row = m0 + wave * 32 + mi * 16 + kg * 4 + r;
        const int col = n0 + ni * 16 + row16;
        float v = acc[mi][ni][r];
        if (EPI == 0) {
          C[(size_t)row * ldc + col] = v;
        } else if (EPI == 1) {
          C2[row * H_ + col] = f2bf(v);
        } else {
          float tv = tanhf(v);
          C[(size_t)row * ldc + col] = tv;
          C2[row * H_ + col] = f2bf(tv);
        }
      }
    }
  }
}

// ---------------------------------------------------------------- LSTM pointwise
__global__ __launch_bounds__(256) void lstm_pw(const float* __restrict__ gates,
                                               const float* __restrict__ b_ih,
                                               const float* __restrict__ b_hh,
                                               float* __restrict__ c,
                                               float* __restrict__ h32,
                                               u16* __restrict__ hbf) {
  const int idx = blockIdx.x * 256 + threadIdx.x;
  const int n = idx & (H_ - 1);
  const float* gb = gates + (size_t)(idx >> 10) * (4 * H_);
  float iv = gb[n]           + b_ih[n]           + b_hh[n];
  float fv = gb[H_ + n]      + b_ih[H_ + n]      + b_hh[H_ + n];
  float gv = gb[2 * H_ + n]  + b_ih[2 * H_ + n]  + b_hh[2 * H_ + n];
  float ov = gb[3 * H_ + n]  + b_ih[3 * H_ + n]  + b_hh[3 * H_ + n];
  iv = sigmoidf_(iv); fv = sigmoidf_(fv); gv = tanhf(gv); ov = sigmoidf_(ov);
  float cn = fv * c[idx] + iv * gv;
  c[idx] = cn;
  float hn = ov * tanhf(cn);
  h32[idx] = hn;
  hbf[idx] = f2bf(hn);
}

// ---------------------------------------------------------------- attention
// Online-softmax single pass. Grid=B, block=1024 (16 waves, 4/SIMD). Each wave
// keeps running (m, l, acc[16]) over s = wave, wave+16, ... Per row: one 32B
// load/lane, 16-FMA score, 64-lane shfl reduce, rescale-on-new-max (rare,
// wave-uniform branch), 16-FMA accumulate. LDS merge of 16 wave-partials.
template <int ISBF>
__global__ __launch_bounds__(1024) void attn_on(const void* __restrict__ ctxv,
                                                const u16* __restrict__ target,
                                                const int* __restrict__ src_len,
                                                u16* __restrict__ wbf) {
  __shared__ float facc[16][1024];
  __shared__ float fm[16], fl[16];
  const int b = blockIdx.x;
  const int tid = threadIdx.x;
  const int lane = tid & 63;
  const int wave = tid >> 6;
  const int len = src_len[b];
  float tg[16];
  {
    const u16* tp = target + b * H_ + lane * 16;
    short8 v1 = *(const short8*)tp;
    short8 v2 = *(const short8*)(tp + 8);
#pragma unroll
    for (int j = 0; j < 8; ++j) { tg[j] = bf2f((u16)v1[j]); tg[8 + j] = bf2f((u16)v2[j]); }
  }
  float m = -1e30f, l = 0.f;
  float acc[16];
#pragma unroll
  for (int j = 0; j < 16; ++j) acc[j] = 0.f;

  for (int s = wave; s < len; s += 16) {
    float cf[16];
    if (ISBF) {
      const u16* cr = (const u16*)ctxv + (size_t)b * (S_ * H_) + (size_t)s * H_ + lane * 16;
      short8 v1 = *(const short8*)cr;
      short8 v2 = *(const short8*)(cr + 8);
#pragma unroll
      for (int j = 0; j < 8; ++j) { cf[j] = bf2f((u16)v1[j]); cf[8 + j] = bf2f((u16)v2[j]); }
    } else {
      const float* cr = (const float*)ctxv + (size_t)b * (S_ * H_) + (size_t)s * H_ + lane * 16;
      float4 w0 = *(const float4*)cr;
      float4 w1 = *(const float4*)(cr + 4);
      float4 w2 = *(const float4*)(cr + 8);
      float4 w3 = *(const float4*)(cr + 12);
      cf[0] = w0.x; cf[1] = w0.y; cf[2] = w0.z; cf[3] = w0.w;
      cf[4] = w1.x; cf[5] = w1.y; cf[6] = w1.z; cf[7] = w1.w;
      cf[8] = w2.x; cf[9] = w2.y; cf[10] = w2.z; cf[11] = w2.w;
      cf[12] = w3.x; cf[13] = w3.y; cf[14] = w3.z; cf[15] = w3.w;
    }
    float x = 0.f;
#pragma unroll
    for (int j = 0; j < 16; ++j) x += cf[j] * tg[j];
#pragma unroll
    for (int off = 1; off < 64; off <<= 1) x += __shfl_xor(x, off);
    if (x > m) {                      // wave-uniform (x uniform after reduce)
      float sc_ = __expf(m - x);      // first hit: exp(-1e30-x) = 0
      l *= sc_;
#pragma unroll
      for (int j = 0; j < 16; ++j) acc[j] *= sc_;
      m = x;
    }
    float p = __expf(x - m);
    l += p;
#pragma unroll
    for (int j = 0; j < 16; ++j) acc[j] += p * cf[j];
  }
  if (lane == 0) { fm[wave] = m; fl[wave] = l; }
#pragma unroll
  for (int j4 = 0; j4 < 4; ++j4) {
    float4 v;
    v.x = acc[j4 * 4]; v.y = acc[j4 * 4 + 1]; v.z = acc[j4 * 4 + 2]; v.w = acc[j4 * 4 + 3];
    *(float4*)&facc[wave][lane * 16 + j4 * 4] = v;
  }
  __syncthreads();
  float mstar = -1e30f;
#pragma unroll
  for (int w = 0; w < 16; ++w) mstar = fmaxf(mstar, fm[w]);
  float lsum = 0.f, asum = 0.f;
#pragma unroll
  for (int w = 0; w < 16; ++w) {
    float e = __expf(fm[w] - mstar);  // empty waves: exp(-1e30) = 0
    lsum += fl[w] * e;
    asum += facc[w][tid] * e;
  }
  wbf[b * H_ + tid] = f2bf(asum / lsum);
}

// ---------------------------------------------------------------- host
extern "C" void kernel_launch(void* const* d_in, const int* in_sizes, int n_in,
                              void* d_out, int out_size, void* d_ws, size_t ws_size,
                              hipStream_t stream) {
  const float* trg_emb = (const float*)d_in[0];
  const float* h0      = (const float*)d_in[1];
  const float* c0      = (const float*)d_in[2];
  const float* ctx     = (const float*)d_in[3];
  const int*   src_len = (const int*)d_in[4];
  const float* W_ih    = (const float*)d_in[5];
  const float* W_hh    = (const float*)d_in[6];
  const float* b_ih    = (const float*)d_in[7];
  const float* b_hh    = (const float*)d_in[8];
  const float* W_in    = (const float*)d_in[9];
  const float* W_out   = (const float*)d_in[10];
  float* out = (float*)d_out;

  char* w = (char*)d_ws;
  u16*   wWih  = (u16*)(w);                 // 4096*1536*2 = 12582912
  u16*   wWhh  = (u16*)(w + 12582912);      // 4096*1024*2 =  8388608
  u16*   wWin  = (u16*)(w + 20971520);      // 1024*1024*2 =  2097152
  u16*   wWout = (u16*)(w + 23068672);      // 1024*2048*2 =  4194304
  u16*   wemb  = (u16*)(w + 27262976);      // 256*16*512*2 = 4194304
  float* wgates= (float*)(w + 31457280);    // 256*4096*4  =  4194304
  float* wh32  = (float*)(w + 35651584);    // 256*1024*4  =  1048576
  float* wc    = (float*)(w + 36700160);    // 1048576
  u16*   whbf  = (u16*)(w + 37748736);      // 524288
  u16*   whtbf = (u16*)(w + 38273024);      // 524288
  u16*   wtgt  = (u16*)(w + 38797312);      // 524288
  u16*   wwbf  = (u16*)(w + 39321600);      // 524288
  u16*   wctx  = (u16*)(w + 39845888);      // 256*512*1024*2 = 268435456
  const bool ctx_bf = ws_size >= (size_t)39845888 + (size_t)268435456;

  auto cvt_launch = [&](const float* s, u16* d, int n) {
    int n4 = n / 4;
    int grid = (n4 + 255) / 256;
    if (grid > 4096) grid = 4096;
    cvt_bf16<<<dim3(grid), dim3(256), 0, stream>>>((const float4*)s, (ushort4*)d, n4);
  };
  cvt_launch(W_ih,  wWih,  4096 * 1536);
  cvt_launch(W_hh,  wWhh,  4096 * 1024);
  cvt_launch(W_in,  wWin,  1024 * 1024);
  cvt_launch(W_out, wWout, 1024 * 2048);
  cvt_launch(trg_emb, wemb, B_ * T_ * E_);
  if (ctx_bf) cvt_launch(ctx, wctx, B_ * S_ * H_);
  init_state<<<dim3((B_ * H_) / 256), dim3(256), 0, stream>>>(h0, c0, wh32, wc, whbf, whtbf);

  Region dummy = { nullptr, 0, nullptr, 0, 0 };
  for (int t = 0; t < T_; ++t) {
    // gates = [emb_t, htilde] @ W_ih^T + h @ W_hh^T  (biases in lstm_pw)
    Region g0 = { wemb + (size_t)t * E_, T_ * E_, wWih,      E_ + H_, E_ };
    Region g1 = { whtbf,                 H_,      wWih + E_, E_ + H_, H_ };
    Region g2 = { whbf,                  H_,      wWhh,      H_,      H_ };
    gemm_ms<0><<<dim3((4 * H_ / 32) * 2), dim3(256), 0, stream>>>(g0, g1, g2, 3, wgates, 4 * H_, (u16*)nullptr);
    lstm_pw<<<dim3((B_ * H_) / 256), dim3(256), 0, stream>>>(wgates, b_ih, b_hh, wc, wh32, whbf);
    // target = h @ W_in^T
    Region i0 = { whbf, H_, wWin, H_, H_ };
    gemm_ms<1><<<dim3((H_ / 32) * 2), dim3(256), 0, stream>>>(i0, dummy, dummy, 1, (float*)nullptr, 0, wtgt);
    if (ctx_bf)
      attn_on<1><<<dim3(B_), dim3(1024), 0, stream>>>((const void*)wctx, wtgt, src_len, wwbf);
    else
      attn_on<0><<<dim3(B_), dim3(1024), 0, stream>>>((const void*)ctx, wtgt, src_len, wwbf);
    // htilde = tanh([weighted, h] @ W_out^T) -> out[:, t, :] and feed-back
    Region o0 = { wwbf, H_, wWout,      2 * H_, H_ };
    Region o1 = { whbf, H_, wWout + H_, 2 * H_, H_ };
    gemm_ms<2><<<dim3((H_ / 32) * 2), dim3(256), 0, stream>>>(o0, o1, dummy, 2,
                                                              out + (size_t)t * H_, T_ * H_, whtbf);
  }
  hipMemcpyAsync(out + (size_t)B_ * T_ * H_, wh32, (size_t)B_ * H_ * sizeof(float),
                 hipMemcpyDeviceToDevice, stream);
  hipMemcpyAsync(out + (size_t)B_ * T_ * H_ + B_ * H_, wc, (size_t)B_ * H_ * sizeof(float),
                 hipMemcpyDeviceToDevice, stream);
}

// Round 3
// 2133.850 us; speedup vs baseline: 1.5544x; 1.1079x over previous
//
#include <hip/hip_runtime.h>
#include <cstdint>
#include <cstddef>

// CCDecoder: 16-step input-feeding LSTM + Luong attention decoder.
// B=256, S=512, T=16, H=1024, E=512.
// R3: emb@W_ihE hoisted to one pre-GEMM (K 2560->2048 per step);
//     LSTM pointwise fused into gates-GEMM epilogue (gate-interleaved weights);
//     GEMM k-loop triple-buffered with raw s_barrier + counted vmcnt (T3/T4);
//     attention gets explicit depth-1 prefetch.

#define B_ 256
#define S_ 512
#define T_ 16
#define H_ 1024
#define E_ 512

typedef unsigned short u16;
using short8 = __attribute__((ext_vector_type(8))) short;
using f32x4  = __attribute__((ext_vector_type(4))) float;

__device__ __forceinline__ float bf2f(u16 u) {
  union { uint32_t i; float f; } v; v.i = ((uint32_t)u) << 16; return v.f;
}
__device__ __forceinline__ u16 f2bf(float f) {
  union { uint32_t i; float f; } v; v.f = f;
  uint32_t r = v.i + 0x7fffu + ((v.i >> 16) & 1u);
  return (u16)(r >> 16);
}
__device__ __forceinline__ float sigmoidf_(float x) { return 1.f / (1.f + __expf(-x)); }

__device__ __forceinline__ void gload_lds16(const void* g, void* l) {
  __builtin_amdgcn_global_load_lds(
      (const __attribute__((address_space(1))) void*)g,
      (__attribute__((address_space(3))) void*)l, 16, 0, 0);
}

// ---------------------------------------------------------------- converts
__global__ __launch_bounds__(256) void cvt_bf16(const float4* __restrict__ src,
                                                ushort4* __restrict__ dst, int n4) {
  for (int i = blockIdx.x * 256 + threadIdx.x; i < n4; i += gridDim.x * 256) {
    float4 v = src[i];
    ushort4 o; o.x = f2bf(v.x); o.y = f2bf(v.y); o.z = f2bf(v.z); o.w = f2bf(v.w);
    dst[i] = o;
  }
}

// row-remapped convert: dst row' = (r&1023)*4 + (r>>10)  (gate-interleave i,f,g,o)
__global__ __launch_bounds__(256) void cvt_rows_gi(const float* __restrict__ src,
                                                   u16* __restrict__ dst, int cols) {
  const int r = blockIdx.x;
  const int rp = (r & 1023) * 4 + (r >> 10);
  const float4* s4 = (const float4*)(src + (size_t)r * cols);
  ushort4* d4 = (ushort4*)(dst + (size_t)rp * cols);
  for (int c = threadIdx.x; c < (cols >> 2); c += 256) {
    float4 v = s4[c];
    ushort4 o; o.x = f2bf(v.x); o.y = f2bf(v.y); o.z = f2bf(v.z); o.w = f2bf(v.w);
    d4[c] = o;
  }
}

__global__ __launch_bounds__(256) void bias_gi(const float* __restrict__ b_ih,
                                               const float* __restrict__ b_hh,
                                               float* __restrict__ bsum) {
  const int r = blockIdx.x * 256 + threadIdx.x;  // 4096
  const int cp = (r & 1023) * 4 + (r >> 10);
  bsum[cp] = b_ih[r] + b_hh[r];
}

__global__ __launch_bounds__(256) void init_state(const float* __restrict__ h0,
                                                  const float* __restrict__ c0,
                                                  float* __restrict__ h32,
                                                  float* __restrict__ c,
                                                  u16* __restrict__ hbf,
                                                  u16* __restrict__ htbf) {
  int idx = blockIdx.x * 256 + threadIdx.x;
  float hv = h0[idx];
  h32[idx] = hv;
  c[idx] = c0[idx];
  u16 hb = f2bf(hv);
  hbf[idx] = hb;
  htbf[idx] = hb;
}

// ---------------------------------------------------------------- GEMM
// C[M, N] = sum_regions A_r (M x klen_r, bf16) * B_r^T (N x klen_r, bf16)
// BM=128, BN=32, 4 waves (32 rows x 32 cols each). Triple-buffered LDS,
// raw s_barrier + counted vmcnt (5 uniform loads/thread per stage):
//   stage(t+2); vmcnt(10); barrier; compute(t); barrier;
// XOR swizzle (chunk ^= row&7) on pre-swizzled global source + swizzled
// ds_read (both-sides rule) kills the 128B-row-stride bank conflict.
struct Region {
  const u16* A; int lda;
  const u16* Bw; int ldb;
  int klen;                // multiple of 64
};

// EPI: 0 fp32 store (pre-GEMM)  1 bf16 store (target)
//      2 tanh -> fp32 out + bf16 htilde  3 fused LSTM (c,h update)
template <int EPI>
__global__ __launch_bounds__(256) void gemm_ms(Region r0, Region r1, Region r2, int nreg,
                                               int nmb,
                                               float* __restrict__ C, int ldc,
                                               u16* __restrict__ C2,
                                               const float* __restrict__ Ci, int cis,
                                               const float* __restrict__ bsum,
                                               float* __restrict__ cst,
                                               float* __restrict__ h32o,
                                               u16* __restrict__ hbfo) {
  __shared__ u16 smA[3][128 * 64];
  __shared__ u16 smB[3][32 * 64];
  const int tid = threadIdx.x;
  const int lane = tid & 63;
  const int wave = tid >> 6;
  const int m0 = (blockIdx.x % nmb) * 128;
  const int n0 = (blockIdx.x / nmb) * 32;

  Region rr[3] = { r0, r1, r2 };
  int tcnt[3];
  int nt = 0;
#pragma unroll
  for (int rg = 0; rg < 3; ++rg) { tcnt[rg] = (rg < nreg) ? (rr[rg].klen >> 6) : 0; nt += tcnt[rg]; }

  auto stage = [&](int lin, int buf) {
    int rg = 0, base = 0;
    while (lin >= base + tcnt[rg]) { base += tcnt[rg]; ++rg; }
    const int kr = (lin - base) << 6;
    const u16* A = rr[rg].A;  const int lda = rr[rg].lda;
    const u16* Bw = rr[rg].Bw; const int ldb = rr[rg].ldb;
#pragma unroll
    for (int j = 0; j < 4; ++j) {            // A: 128x64 = 1024 chunks, 4/thread
      const int c = j * 256 + tid;
      const int row = c >> 3;
      const int q = (c & 7) ^ (row & 7);
      gload_lds16(A + (size_t)(m0 + row) * lda + kr + q * 8,
                  (char*)&smA[buf][0] + (size_t)(j * 256 + wave * 64) * 16);
    }
    {                                        // B: 32x64 = 256 chunks, 1/thread
      const int row = tid >> 3;
      const int q = (tid & 7) ^ (row & 7);
      gload_lds16(Bw + (size_t)(n0 + row) * ldb + kr + q * 8,
                  (char*)&smB[buf][0] + (size_t)(wave * 64) * 16);
    }
  };

  f32x4 acc[2][2] = {};
  stage(0, 0);
  if (nt > 1) stage(1, 1);
  for (int ti = 0; ti < nt; ++ti) {
    const int buf = ti % 3;
    if (ti + 2 < nt) {
      stage(ti + 2, (ti + 2) % 3);
      asm volatile("s_waitcnt vmcnt(10)" ::: "memory");
    } else if (ti + 1 < nt) {
      asm volatile("s_waitcnt vmcnt(5)" ::: "memory");
    } else {
      asm volatile("s_waitcnt vmcnt(0)" ::: "memory");
    }
    __builtin_amdgcn_s_barrier();
    const int row16 = lane & 15;
#pragma unroll
    for (int ks = 0; ks < 2; ++ks) {
      const int q = ks * 4 + (lane >> 4);
      short8 af[2], bfr[2];
#pragma unroll
      for (int mi = 0; mi < 2; ++mi) {
        const int R = wave * 32 + mi * 16 + row16;
        af[mi] = *(const short8*)((const char*)&smA[buf][0] + (size_t)(R * 8 + (q ^ (R & 7))) * 16);
      }
#pragma unroll
      for (int ni = 0; ni < 2; ++ni) {
        const int Rn = ni * 16 + row16;
        bfr[ni] = *(const short8*)((const char*)&smB[buf][0] + (size_t)(Rn * 8 + (q ^ (Rn & 7))) * 16);
      }
#pragma unroll
      for (int mi = 0; mi < 2; ++mi)
#pragma unroll
        for (int ni = 0; ni < 2; ++ni)
          acc[mi][ni] = __builtin_amdgcn_mfma_f32_16x16x32_bf16(af[mi], bfr[ni], acc[mi][ni], 0, 0, 0);
    }
    __builtin_amdgcn_s_barrier();
  }
  // C/D layout: col = lane&15, row = (lane>>4)*4 + r  [m89-verified]
  const int row16 = lane & 15;
  const int kg = lane >> 4;
#pragma unroll
  for (int mi = 0; mi < 2; ++mi) {
#pragma unroll
    for (int ni = 0; ni < 2; ++ni) {
#pragma unroll
      for (int r = 0; r < 4; ++r) {
        const int row = m0 + wave * 32 + mi * 16 + kg * 4 + r;
        const int col = n0 + ni * 16 + row16;
        float v = acc[mi][ni][r];
        if (EPI == 0) {
          C[(size_t)row * ldc + col] = v;
        } else if (EPI == 1) {
          C2[row * H_ + col] = f2bf(v);
        } else if (EPI == 2) {
          float tv = tanhf(v);
          C[(size_t)row * ldc + col] = tv;
          C2[row * H_ + col] = f2bf(tv);
        } else {
          // fused LSTM: v = gate value (gate = col&3, unit = col>>2)
          v += Ci[(size_t)row * cis + col] + bsum[col];
          float v1 = __shfl_xor(v, 1);
          float v2 = __shfl_xor(v, 2);
          float v3 = __shfl_xor(v, 3);
          if ((row16 & 3) == 0) {           // this lane's v,v1,v2,v3 = i,f,g,o
            const int u = (n0 + ni * 16 + (row16 & ~3)) >> 2;
            float iv = sigmoidf_(v);
            float fv = sigmoidf_(v1);
            float gv = tanhf(v2);
            float ov = sigmoidf_(v3);
            float cn = fv * cst[row * H_ + u] + iv * gv;
            float hn = ov * tanhf(cn);
            cst[row * H_ + u] = cn;
            h32o[row * H_ + u] = hn;
            hbfo[row * H_ + u] = f2bf(hn);
          }
        }
      }
    }
  }
}

// ---------------------------------------------------------------- attention
// Online-softmax single pass. Grid=B, block=1024 (16 waves). Depth-1 row
// prefetch. Per row: 32B/lane load, 16-FMA dot, 64-lane shfl reduce,
// rescale-on-new-max (wave-uniform), 16-FMA accumulate. LDS merge at end.
template <int ISBF>
__global__ __launch_bounds__(1024) void attn_on(const void* __restrict__ ctxv,
                                                const u16* __restrict__ target,
                                                const int* __restrict__ src_len,
                                                u16* __restrict__ wbf) {
  __shared__ float facc[16][1024];
  __shared__ float fm[16], fl[16];
  const int b = blockIdx.x;
  const int tid = threadIdx.x;
  const int lane = tid & 63;
  const int wave = tid >> 6;
  const int len = src_len[b];
  float tg[16];
  {
    const u16* tp = target + b * H_ + lane * 16;
    short8 v1 = *(const short8*)tp;
    short8 v2 = *(const short8*)(tp + 8);
#pragma unroll
    for (int j = 0; j < 8; ++j) { tg[j] = bf2f((u16)v1[j]); tg[8 + j] = bf2f((u16)v2[j]); }
  }
  float m = -1e30f, l = 0.f;
  float acc[16];
#pragma unroll
  for (int j = 0; j < 16; ++j) acc[j] = 0.f;

  if (ISBF) {
    const u16* cb = (const u16*)ctxv + (size_t)b * (S_ * H_);
    int s = wave;
    short8 c1 = {}, c2 = {};
    if (s < len) {
      const u16* p = cb + (size_t)s * H_ + lane * 16;
      c1 = *(const short8*)p; c2 = *(const short8*)(p + 8);
    }
    while (s < len) {
      const int sn = s + 16;
      short8 n1 = {}, n2 = {};
      if (sn < len) {
        const u16* p = cb + (size_t)sn * H_ + lane * 16;
        n1 = *(const short8*)p; n2 = *(const short8*)(p + 8);
      }
      float cf[16];
#pragma unroll
      for (int j = 0; j < 8; ++j) { cf[j] = bf2f((u16)c1[j]); cf[8 + j] = bf2f((u16)c2[j]); }
      float x = 0.f;
#pragma unroll
      for (int j = 0; j < 16; ++j) x += cf[j] * tg[j];
#pragma unroll
      for (int off = 1; off < 64; off <<= 1) x += __shfl_xor(x, off);
      if (x > m) {                      // wave-uniform after reduce
        float sc_ = __expf(m - x);
        l *= sc_;
#pragma unroll
        for (int j = 0; j < 16; ++j) acc[j] *= sc_;
        m = x;
      }
      float p = __expf(x - m);
      l += p;
#pragma unroll
      for (int j = 0; j < 16; ++j) acc[j] += p * cf[j];
      s = sn; c1 = n1; c2 = n2;
    }
  } else {
    const float* cb = (const float*)ctxv + (size_t)b * (S_ * H_);
    for (int s = wave; s < len; s += 16) {
      const float* cr = cb + (size_t)s * H_ + lane * 16;
      float cf[16];
#pragma unroll
      for (int j4 = 0; j4 < 4; ++j4) {
        float4 v = *(const float4*)(cr + j4 * 4);
        cf[j4 * 4] = v.x; cf[j4 * 4 + 1] = v.y; cf[j4 * 4 + 2] = v.z; cf[j4 * 4 + 3] = v.w;
      }
      float x = 0.f;
#pragma unroll
      for (int j = 0; j < 16; ++j) x += cf[j] * tg[j];
#pragma unroll
      for (int off = 1; off < 64; off <<= 1) x += __shfl_xor(x, off);
      if (x > m) {
        float sc_ = __expf(m - x);
        l *= sc_;
#pragma unroll
        for (int j = 0; j < 16; ++j) acc[j] *= sc_;
        m = x;
      }
      float p = __expf(x - m);
      l += p;
#pragma unroll
      for (int j = 0; j < 16; ++j) acc[j] += p * cf[j];
    }
  }
  if (lane == 0) { fm[wave] = m; fl[wave] = l; }
#pragma unroll
  for (int j4 = 0; j4 < 4; ++j4) {
    float4 v;
    v.x = acc[j4 * 4]; v.y = acc[j4 * 4 + 1]; v.z = acc[j4 * 4 + 2]; v.w = acc[j4 * 4 + 3];
    *(float4*)&facc[wave][lane * 16 + j4 * 4] = v;
  }
  __syncthreads();
  float mstar = -1e30f;
#pragma unroll
  for (int w = 0; w < 16; ++w) mstar = fmaxf(mstar, fm[w]);
  float lsum = 0.f, asum = 0.f;
#pragma unroll
  for (int w = 0; w < 16; ++w) {
    float e = __expf(fm[w] - mstar);
    lsum += fl[w] * e;
    asum += facc[w][tid] * e;
  }
  wbf[b * H_ + tid] = f2bf(asum / lsum);
}

// ---------------------------------------------------------------- host
extern "C" void kernel_launch(void* const* d_in, const int* in_sizes, int n_in,
                              void* d_out, int out_size, void* d_ws, size_t ws_size,
                              hipStream_t stream) {
  const float* trg_emb = (const float*)d_in[0];
  const float* h0      = (const float*)d_in[1];
  const float* c0      = (const float*)d_in[2];
  const float* ctx     = (const float*)d_in[3];
  const int*   src_len = (const int*)d_in[4];
  const float* W_ih    = (const float*)d_in[5];
  const float* W_hh    = (const float*)d_in[6];
  const float* b_ih    = (const float*)d_in[7];
  const float* b_hh    = (const float*)d_in[8];
  const float* W_in    = (const float*)d_in[9];
  const float* W_out   = (const float*)d_in[10];
  float* out = (float*)d_out;

  char* w = (char*)d_ws;
  u16*   wWih  = (u16*)(w);                 // 12,582,912
  u16*   wWhh  = (u16*)(w + 12582912);      //  8,388,608
  u16*   wWin  = (u16*)(w + 20971520);      //  2,097,152
  u16*   wWout = (u16*)(w + 23068672);      //  4,194,304
  u16*   wemb  = (u16*)(w + 27262976);      //  4,194,304
  float* wbsum = (float*)(w + 31457280);    //     16,384
  float* wh32  = (float*)(w + 31473664);    //  1,048,576
  float* wc    = (float*)(w + 32522240);    //  1,048,576
  u16*   whbf  = (u16*)(w + 33570816);      //    524,288
  u16*   whtbf = (u16*)(w + 34095104);      //    524,288
  u16*   wtgt  = (u16*)(w + 34619392);      //    524,288
  u16*   wwbf  = (u16*)(w + 35143680);      //    524,288
  float* wGemb = (float*)(w + 35667968);    // 67,108,864
  u16*   wctx  = (u16*)(w + 102776832);     // 268,435,456
  const bool ctx_bf = ws_size >= (size_t)102776832 + (size_t)268435456;

  auto cvt_launch = [&](const float* s, u16* d, int n) {
    int n4 = n / 4;
    int grid = (n4 + 255) / 256;
    if (grid > 4096) grid = 4096;
    cvt_bf16<<<dim3(grid), dim3(256), 0, stream>>>((const float4*)s, (ushort4*)d, n4);
  };
  cvt_rows_gi<<<dim3(4096), dim3(256), 0, stream>>>(W_ih, wWih, 1536);
  cvt_rows_gi<<<dim3(4096), dim3(256), 0, stream>>>(W_hh, wWhh, 1024);
  bias_gi<<<dim3(16), dim3(256), 0, stream>>>(b_ih, b_hh, wbsum);
  cvt_launch(W_in,  wWin,  1024 * 1024);
  cvt_launch(W_out, wWout, 1024 * 2048);
  cvt_launch(trg_emb, wemb, B_ * T_ * E_);
  if (ctx_bf) cvt_launch(ctx, wctx, B_ * S_ * H_);
  init_state<<<dim3((B_ * H_) / 256), dim3(256), 0, stream>>>(h0, c0, wh32, wc, whbf, whtbf);

  Region dummy = { nullptr, 0, nullptr, 0, 0 };
  // G_emb[b*16+t, :] = emb @ W_ihE^T  (M=4096, N=4096, K=512)
  {
    Region e0 = { wemb, E_, wWih, E_ + H_, E_ };
    gemm_ms<0><<<dim3(32 * 128), dim3(256), 0, stream>>>(
        e0, dummy, dummy, 1, 32, wGemb, 4096, (u16*)nullptr,
        nullptr, 0, nullptr, nullptr, nullptr, nullptr);
  }

  for (int t = 0; t < T_; ++t) {
    // gates = G_emb[.,t] + htilde @ W_ihH^T + h @ W_hh^T  (+bias) -> fused LSTM
    Region g0 = { whtbf, H_, wWih + E_, E_ + H_, H_ };
    Region g1 = { whbf,  H_, wWhh,      H_,      H_ };
    gemm_ms<3><<<dim3(2 * 128), dim3(256), 0, stream>>>(
        g0, g1, dummy, 2, 2, nullptr, 0, (u16*)nullptr,
        wGemb + (size_t)t * 4096, T_ * 4096, wbsum, wc, wh32, whbf);
    // target = h @ W_in^T
    Region i0 = { whbf, H_, wWin, H_, H_ };
    gemm_ms<1><<<dim3(2 * 32), dim3(256), 0, stream>>>(
        i0, dummy, dummy, 1, 2, nullptr, 0, wtgt,
        nullptr, 0, nullptr, nullptr, nullptr, nullptr);
    if (ctx_bf)
      attn_on<1><<<dim3(B_), dim3(1024), 0, stream>>>((const void*)wctx, wtgt, src_len, wwbf);
    else
      attn_on<0><<<dim3(B_), dim3(1024), 0, stream>>>((const void*)ctx, wtgt, src_len, wwbf);
    // htilde = tanh([weighted, h] @ W_out^T) -> out[:, t, :] and feed-back
    Region o0 = { wwbf, H_, wWout,      2 * H_, H_ };
    Region o1 = { whbf, H_, wWout + H_, 2 * H_, H_ };
    gemm_ms<2><<<dim3(2 * 32), dim3(256), 0, stream>>>(
        o0, o1, dummy, 2, 2, out + (size_t)t * H_, T_ * H_, whtbf,
        nullptr, 0, nullptr, nullptr, nullptr, nullptr);
  }
  hipMemcpyAsync(out + (size_t)B_ * T_ * H_, wh32, (size_t)B_ * H_ * sizeof(float),
                 hipMemcpyDeviceToDevice, stream);
  hipMemcpyAsync(out + (size_t)B_ * T_ * H_ + B_ * H_, wc, (size_t)B_ * H_ * sizeof(float),
                 hipMemcpyDeviceToDevice, stream);
}